// Round 3
// baseline (215.688 us; speedup 1.0000x reference)
//
#include <hip/hip_runtime.h>

// DILATE loss: 0.5*soft-DTW(value) + 0.5*<softDTW-grad, Omega>.
// B=64, T=128, C=4 -> M=256 independent sequences, N=128, gamma=0.01.
//
// Wave-synchronous design: one block = ONE wave (64 lanes), one sequence.
// Lane l owns rows i0=2l+1, i1=2l+2. Anti-diagonal recurrences keep all
// rolling state (prev diagonals of R, E) in registers; cross-row neighbors
// move via __shfl_up/__shfl_down. No __syncthreads inside either 255-step
// loop (single wave executes in lockstep). R is stored to LDS during the
// forward pass (write-only) and read back 2 values/step (prefetched) in the
// backward pass; diag d+1/d+2 R values are register-rotated from earlier
// reads, so the LDS latency is off the serial chain.

#define TN 128      // sequence length N
#define RS 130      // (row stride concept; actual addressing is 129*i + d)
#define BATCH 64
#define CH 4

// glibc reserves __exp2f/__log2f as macros — use the amdgcn builtins
// (single v_exp_f32 / v_log_f32) with a libm fallback.
__device__ __forceinline__ float fast_exp2(float x) {
#if __has_builtin(__builtin_amdgcn_exp2f)
  return __builtin_amdgcn_exp2f(x);
#else
  return exp2f(x);
#endif
}
__device__ __forceinline__ float fast_log2(float x) {
#if __has_builtin(__builtin_amdgcn_logf)
  return __builtin_amdgcn_logf(x);
#else
  return log2f(x);
#endif
}

__global__ __launch_bounds__(64)
void dilate_softdtw_kernel(const float* __restrict__ outputs,
                           const float* __restrict__ targets,
                           float* __restrict__ out) {
  __shared__ float Rs[(TN + 1) * RS];   // rows 1..128, cols 1..128 used (67 KB)
  __shared__ float t_s[TN];
  __shared__ float o_s[TN];

  const float BIG  = 100000000.0f;
  const float K2   = 144.269504089f;    // (1/gamma) * log2(e) = 100*log2(e)
  const float GLN2 = 0.0069314718056f;  // gamma * ln(2)

  const int m    = blockIdx.x;    // sequence 0..255
  const int b    = m >> 2;
  const int c    = m & 3;
  const int lane = threadIdx.x;   // 0..63
  const int i0   = 2 * lane + 1;
  const int i1   = 2 * lane + 2;

  // t[i] = targets[b][i][c], o[j] = outputs[b][j][c]
  const float* tb = targets + (size_t)b * (TN * CH) + c;
  const float* ob = outputs + (size_t)b * (TN * CH) + c;
  t_s[lane]      = tb[lane * CH];
  t_s[lane + 64] = tb[(lane + 64) * CH];
  o_s[lane]      = ob[lane * CH];
  o_s[lane + 64] = ob[(lane + 64) * CH];
  __syncthreads();   // single wave: cheap

  const float t0 = t_s[i0 - 1];                   // t[i0]
  const float t1 = t_s[i1 - 1];                   // t[i1] = t[i0+1]
  const float t1p = (i1 < TN) ? t_s[i1] : 0.0f;   // t[i1+1]

  const int base0 = 129 * i0;   // Rs[addr] for (i0, j0=d-i0)  ->  base0 + d
  const int base1 = 129 * i1;   // for (i1, j1=d-i1)           ->  base1 + d (d index shifted below)

  // ---------------- forward ----------------
  // p1_x = R[ix][d-1-ix] (diag d-1), p2_x = R[ix][d-2-ix] (diag d-2).
  float p1_0 = BIG, p1_1 = BIG, p2_0 = BIG, p2_1 = BIG;

  for (int d = 2; d <= 2 * TN; ++d) {
    // neighbors from row i0-1 (= lane-1's i1)
    float up1 = __shfl_up(p1_1, 1, 64);   // R[i0-1][j0]   (diag d-1)
    float up2 = __shfl_up(p2_1, 1, 64);   // R[i0-1][j0-1] (diag d-2)
    if (lane == 0) { up1 = BIG; up2 = (d == 2) ? 0.0f : BIG; }

    const int j0 = d - i0;
    const int j1 = j0 - 1;      // = d - i1
    float c0 = BIG, c1 = BIG;

    if (j0 >= 1 && j0 <= TN) {  // cell (i0, j0): softmin(R[i0-1][j0-1], R[i0-1][j0], R[i0][j0-1])
      const float a = up2, bb = up1, cc = p1_0;
      float mn = fminf(a, fminf(bb, cc));
      float s = mn - GLN2 * fast_log2(fast_exp2((mn - a) * K2) +
                                      fast_exp2((mn - bb) * K2) +
                                      fast_exp2((mn - cc) * K2));
      const float df = t0 - o_s[j0 - 1];
      c0 = df * df + s;
      Rs[base0 + d] = c0;       // R[i0][j0]
    }
    if (j1 >= 1 && j1 <= TN) {  // cell (i1, j1): softmin(R[i0][j1-1], R[i0][j1], R[i1][j1-1])
      const float a = p2_0, bb = p1_0, cc = p1_1;
      float mn = fminf(a, fminf(bb, cc));
      float s = mn - GLN2 * fast_log2(fast_exp2((mn - a) * K2) +
                                      fast_exp2((mn - bb) * K2) +
                                      fast_exp2((mn - cc) * K2));
      const float df = t1 - o_s[j1 - 1];
      c1 = df * df + s;
      Rs[base1 + d - 1] = c1;   // R[i1][j1]
    }
    p2_0 = p1_0; p2_1 = p1_1; p1_0 = c0; p1_1 = c1;
  }

  const float rNN = __shfl(p1_1, 63, 64);   // R[128][128]

  __syncthreads();   // order R writes before backward reads (single wave)

  // ---------------- backward ----------------
  // e1_x = E[ix][.] on diag d+1, e2_x on diag d+2 (register-rotated).
  // A1_x = R[ix][.] on diag d+1, A2_x on diag d+2; Rcur_x = R on diag d.
  float e1_0 = 0.f, e1_1 = 0.f, e2_0 = 0.f, e2_1 = 0.f;
  float A1_0 = 0.f, A1_1 = 0.f, A2_0 = 0.f, A2_1 = 0.f;
  float acc = 0.f;

  float Rcur0 = 0.f, Rcur1 = 0.f;
  {
    const int d = 2 * TN;
    const int j0 = d - i0, j1 = j0 - 1;
    if (j0 >= 1 && j0 <= TN) Rcur0 = Rs[base0 + d];
    if (j1 >= 1 && j1 <= TN) Rcur1 = Rs[base1 + d - 1];
  }

  for (int d = 2 * TN; d >= 2; --d) {
    // prefetch diag d-1 (used next iteration) — off the serial chain
    float Rn0 = 0.f, Rn1 = 0.f;
    {
      const int jn0 = d - 1 - i0, jn1 = jn0 - 1;
      if (jn0 >= 1 && jn0 <= TN) Rn0 = Rs[base0 + d - 1];
      if (jn1 >= 1 && jn1 <= TN) Rn1 = Rs[base1 + d - 2];
    }
    // row i1+1 values from lane l+1 (its i0-row regs)
    const float A1n = __shfl_down(A1_0, 1, 64);   // R[i1+1][j1]   (diag d+1)
    const float A2n = __shfl_down(A2_0, 1, 64);   // R[i1+1][j1+1] (diag d+2)
    const float e1n = __shfl_down(e1_0, 1, 64);   // E[i1+1][j1]
    const float e2n = __shfl_down(e2_0, 1, 64);   // E[i1+1][j1+1]

    const int j0 = d - i0;
    const int j1 = j0 - 1;
    float v0 = 0.f, v1 = 0.f;

    if (j0 >= 1 && j0 <= TN) {          // cell (i0, j0); i0 <= 127 so i0 < TN always
      {
        const float oj = o_s[j0 - 1];   // o[j0]
        const float du = t1 - oj;       // t[i0+1] - o[j0]
        v0 = e1_1 * fast_exp2((A1_1 - Rcur0 - du * du) * K2);   // up: R[i1][j0]
      }
      if (j0 < TN) {
        const float op = o_s[j0];       // o[j0+1]
        const float dl = t0 - op;
        v0 += e1_0 * fast_exp2((A1_0 - Rcur0 - dl * dl) * K2);  // left: R[i0][j0+1]
        const float dd = t1 - op;
        v0 += e2_1 * fast_exp2((A2_1 - Rcur0 - dd * dd) * K2);  // diag: R[i1][j0+1]
      }
      const float dij = (float)(i0 - j0);
      acc += v0 * dij * dij;
    }
    if (j1 >= 1 && j1 <= TN) {          // cell (i1, j1)
      if (i1 == TN && j1 == TN) {
        v1 = 1.0f;
      } else {
        if (i1 < TN) {
          const float oj = o_s[j1 - 1];
          const float du = t1p - oj;
          v1 = e1n * fast_exp2((A1n - Rcur1 - du * du) * K2);   // up: R[i1+1][j1]
        }
        if (j1 < TN) {
          const float op = o_s[j1];
          const float dl = t1 - op;
          v1 += e1_1 * fast_exp2((A1_1 - Rcur1 - dl * dl) * K2);  // left: R[i1][j1+1]
          if (i1 < TN) {
            const float dd = t1p - op;
            v1 += e2n * fast_exp2((A2n - Rcur1 - dd * dd) * K2);  // diag: R[i1+1][j1+1]
          }
        }
      }
      const float dij = (float)(i1 - j1);
      acc += v1 * dij * dij;
    }

    // rotate register pipelines
    A2_0 = A1_0; A2_1 = A1_1; A1_0 = Rcur0; A1_1 = Rcur1;
    Rcur0 = Rn0; Rcur1 = Rn1;
    e2_0 = e1_0; e2_1 = e1_1; e1_0 = v0; e1_1 = v1;
  }

  // ---------------- reduce & accumulate ----------------
  #pragma unroll
  for (int off = 32; off > 0; off >>= 1) acc += __shfl_down(acc, off, 64);
  if (lane == 0) {
    const float partial = 0.5f * (rNN / (float)BATCH)
                        + 0.5f * (acc / (float)(BATCH * TN * TN));
    atomicAdd(out, partial);
  }
}

extern "C" void kernel_launch(void* const* d_in, const int* in_sizes, int n_in,
                              void* d_out, int out_size, void* d_ws, size_t ws_size,
                              hipStream_t stream) {
  const float* outputs = (const float*)d_in[0];   // [64,128,4]
  const float* targets = (const float*)d_in[1];   // [64,128,4]
  float* out = (float*)d_out;                     // scalar fp32
  (void)in_sizes; (void)n_in; (void)out_size; (void)d_ws; (void)ws_size;

  // d_out is poisoned to 0xAA before every timed launch — zero it ourselves.
  (void)hipMemsetAsync(out, 0, sizeof(float), stream);
  dilate_softdtw_kernel<<<dim3(256), dim3(64), 0, stream>>>(outputs, targets, out);
}

// Round 4
// 146.609 us; speedup vs baseline: 1.4712x; 1.4712x over previous
//
#include <hip/hip_runtime.h>

// DILATE loss: 0.5*soft-DTW(value) + 0.5*<softDTW-grad, Omega>.
// B=64, T=128, C=4 -> M=256 independent sequences, N=128, gamma=0.01.
//
// One block = one wave = one sequence. Lane l owns rows i0=2l+1, i1=2l+2.
// Forward: anti-diagonal recurrence in registers; cross-lane row handoff via
// DPP wave_shr:1 (VALU, ~4 cyc, boundary fill via `old` operand) instead of
// ds_permute (~60-120 cyc on the serial chain). Per cell, the three softmin
// exp terms are normalized (rcp) and stored to LDS as weights W1=w_diag,
// W2=w_up (w_left = 1-W1-W2): these ARE the soft-DTW backward edge weights
//   exp((R_succ - D_succ - R_cur)/gamma) = exp_k / sum.
// Backward: pure fma recursion on E diagonals in registers + prefetched LDS
// weight reads + one DPP wave_shl:1 per step — ZERO transcendentals.
// LDS: 2*128*130*4 = 133 KB weights + 1 KB t/o  (< 160 KB/CU).

#define TN 128
#define BATCH 64
#define CH 4
#define WROW 130          // W row stride (words): lane stride 258 = 2 mod 32 -> free 2-way
#define WSZ (TN * WROW)   // 16640 words per array

__device__ __forceinline__ float fast_exp2(float x) { return __builtin_amdgcn_exp2f(x); }
__device__ __forceinline__ float fast_log2(float x) { return __builtin_amdgcn_logf(x); }
__device__ __forceinline__ float fast_rcp(float x)  { return __builtin_amdgcn_rcpf(x); }

// lane i <- lane i-1, lane 0 <- fill   (DPP wave_shr:1)
__device__ __forceinline__ float dpp_shr1(float x, float fill) {
  union U { float f; int i; } o, s, r;
  o.f = fill; s.f = x;
  r.i = __builtin_amdgcn_update_dpp(o.i, s.i, 0x138, 0xF, 0xF, false);
  return r.f;
}
// lane i <- lane i+1, lane 63 <- fill  (DPP wave_shl:1)
__device__ __forceinline__ float dpp_shl1(float x, float fill) {
  union U { float f; int i; } o, s, r;
  o.f = fill; s.f = x;
  r.i = __builtin_amdgcn_update_dpp(o.i, s.i, 0x130, 0xF, 0xF, false);
  return r.f;
}

// softmin3 + normalized weights. a=diag pred, b=up pred, c=left pred.
__device__ __forceinline__ float softmin_w(float a, float b, float c,
                                           float& w1, float& w2) {
  const float K2   = 144.2695040888963f;      // (1/gamma)*log2(e)
  const float GLN2 = 0.006931471805599453f;   // gamma*ln(2)
  float mn = fminf(a, fminf(b, c));
  float h  = mn * K2;
  float ea = fast_exp2(__builtin_fmaf(-K2, a, h));   // exp2(K2*(mn-a)) <= 1
  float eb = fast_exp2(__builtin_fmaf(-K2, b, h));
  float ec = fast_exp2(__builtin_fmaf(-K2, c, h));
  float sum = (ea + eb) + ec;                        // in [1,3]
  float rs  = fast_rcp(sum);
  w1 = ea * rs;                                      // w_diag
  w2 = eb * rs;                                      // w_up
  return __builtin_fmaf(-GLN2, fast_log2(sum), mn);  // softmin value
}

__global__ __launch_bounds__(64)
void dilate_softdtw_kernel(const float* __restrict__ outputs,
                           const float* __restrict__ targets,
                           float* __restrict__ out) {
  __shared__ float W1[WSZ];   // w_diag per cell, index (i-1)*130 + (j-1)
  __shared__ float W2[WSZ];   // w_up
  __shared__ float t_s[TN];
  __shared__ float o_s[TN];

  const float BIG = 100000000.0f;

  const int m = blockIdx.x, b = m >> 2, c = m & 3;
  const int lane = threadIdx.x;            // 0..63
  const int i0 = 2*lane + 1, i1 = 2*lane + 2;

  const float* tb = targets + (size_t)b*(TN*CH) + c;
  const float* ob = outputs + (size_t)b*(TN*CH) + c;
  t_s[lane]      = tb[lane*CH];
  t_s[lane + 64] = tb[(lane + 64)*CH];
  o_s[lane]      = ob[lane*CH];
  o_s[lane + 64] = ob[(lane + 64)*CH];
  __syncthreads();

  const float t0 = t_s[i0 - 1];
  const float t1 = t_s[i1 - 1];

  // ---------------- forward (peel d=2) ----------------
  // p1_x = R[ix] on diag d-1, p2_0 = R[i0] on diag d-2, up2 = R[i0-1][j0-1].
  float p1_0, p1_1 = BIG, p2_0 = BIG, up2 = BIG;
  {
    float df = t0 - o_s[0];
    p1_0 = (lane == 0) ? df * df : BIG;    // R[1][1] = D[1][1]
    if (lane == 0) { W1[0] = 1.0f; W2[0] = 0.0f; }
  }

  for (int d = 3; d <= 2*TN; ++d) {
    float up1 = dpp_shr1(p1_1, BIG);        // R[i0-1][j0] (row 0 -> BIG)
    const int j0 = d - i0;                  // c0 column; c1 column = j0-1
    const unsigned a0 = (unsigned)(j0 - 1); // act0: a0 <= 127
    const unsigned a1 = (unsigned)(j0 - 2); // act1
    const float o0 = o_s[j0 - 1];           // OOB reads land in adjacent LDS: benign, masked out
    const float o1 = o_s[j0 - 2];
    const int iw = 258*lane + d - 2;        // (i0-1)*130 + (j0-1)

    // c1 = cell (i1, j0-1): independent of the DPP -> overlaps its latency
    float w1b, w2b;
    float s1  = softmin_w(p2_0, p1_0, p1_1, w1b, w2b);
    float df1 = t1 - o1;
    float c1v = (a1 <= 127u) ? __builtin_fmaf(df1, df1, s1) : BIG;
    if (a1 <= 127u) { W1[iw + 129] = w1b; W2[iw + 129] = w2b; }

    // c0 = cell (i0, j0)
    float w1a, w2a;
    float s0  = softmin_w(up2, up1, p1_0, w1a, w2a);
    float df0 = t0 - o0;
    float c0v = (a0 <= 127u) ? __builtin_fmaf(df0, df0, s0) : BIG;
    if (a0 <= 127u) { W1[iw] = w1a; W2[iw] = w2a; }

    p2_0 = p1_0; p1_0 = c0v; p1_1 = c1v; up2 = up1;
  }
  const float rNN = __shfl(p1_1, 63, 64);   // R[128][128]
  __syncthreads();

  // ---------------- backward: E recursion, weights from LDS ----------------
  // E[i][j] = E[i+1][j]*w_up(i+1,j) + E[i][j+1]*w_left(i,j+1) + E[i+1][j+1]*w_diag(i+1,j+1)
  // e1_* = E on diag d+1, e2_1 = E[i1] on diag d+2; e1n = E[i1+1] diag d+1 (DPP),
  // e2n = E[i1+1] diag d+2 (= previous e1n).
  float e1_0 = 0.f, e1_1 = 0.f, e2_1 = 0.f, e1n_prev = 0.f;
  float cwA1 = 0.f, cwA2 = 0.f, cwB1 = 0.f, cwB2 = 0.f, cwC1 = 0.f, cwD2 = 0.f, cwE1 = 0.f;
  float acc = 0.f;

  for (int d = 2*TN; d >= 2; --d) {
    float e1n = dpp_shl1(e1_0, 0.f);        // E[i1+1][j1] (beyond row 128 -> 0)
    float e2n = e1n_prev;                   // E[i1+1][j1+1]

    // prefetch weights for step d-1 (consumed next iteration)
    const int ibn = 258*lane + d - 1;
    float nA1 = W1[ibn + 128], nA2 = W2[ibn + 128];  // cell (i1, j0')
    float nB1 = W1[ibn - 1],   nB2 = W2[ibn - 1];    // cell (i0, j0'+1)
    float nC1 = W1[ibn + 129];                       // cell (i1, j0'+1)
    float nD2 = W2[ibn + 257];                       // cell (i1+1, j1')
    float nE1 = W1[ibn + 258];                       // cell (i1+1, j0')

    const int j0 = d - i0;
    const unsigned a0 = (unsigned)(j0 - 1);
    const unsigned a1 = (unsigned)(j0 - 2);

    float v0 = 0.f;
    if (a0 <= 127u) {                        // cell (i0, j0); i1 <= 128 always
      v0 = e1_1 * cwA2;                      // up succ (i1, j0)
      if (j0 < TN) {
        v0 = __builtin_fmaf(e1_0, 1.f - cwB1 - cwB2, v0);  // left succ (i0, j0+1)
        v0 = __builtin_fmaf(e2_1, cwC1, v0);               // diag succ (i1, j0+1)
      }
    }
    float v1 = 0.f;
    if (a1 <= 127u) {                        // cell (i1, j1=j0-1)
      if (lane < 63) v1 = e1n * cwD2;                      // up succ (i1+1, j1)
      if (j0 <= TN)  v1 = __builtin_fmaf(e1_1, 1.f - cwA1 - cwA2, v1); // left succ (i1, j0)
      if (lane < 63 && j0 <= TN) v1 = __builtin_fmaf(e2n, cwE1, v1);   // diag succ (i1+1, j0)
    }
    if (lane == 63 && j0 == 129) v1 = 1.0f;  // seed E[128][128] at d=256

    float fd0 = (float)(i0 - j0);
    float fd1 = fd0 + 2.0f;                  // i1 - j1
    acc = __builtin_fmaf(v0, fd0 * fd0, acc);
    acc = __builtin_fmaf(v1, fd1 * fd1, acc);

    e2_1 = e1_1; e1_0 = v0; e1_1 = v1; e1n_prev = e1n;
    cwA1 = nA1; cwA2 = nA2; cwB1 = nB1; cwB2 = nB2; cwC1 = nC1; cwD2 = nD2; cwE1 = nE1;
  }

  // ---------------- reduce & accumulate ----------------
  #pragma unroll
  for (int off = 32; off > 0; off >>= 1) acc += __shfl_down(acc, off, 64);
  if (lane == 0) {
    // 0.5*rNN/B + 0.5*acc/(B*T*T)
    const float partial = rNN * 0.0078125f + acc * 4.76837158203125e-7f;
    atomicAdd(out, partial);
  }
}

extern "C" void kernel_launch(void* const* d_in, const int* in_sizes, int n_in,
                              void* d_out, int out_size, void* d_ws, size_t ws_size,
                              hipStream_t stream) {
  const float* outputs = (const float*)d_in[0];   // [64,128,4]
  const float* targets = (const float*)d_in[1];   // [64,128,4]
  float* out = (float*)d_out;                     // scalar fp32
  (void)in_sizes; (void)n_in; (void)out_size; (void)d_ws; (void)ws_size;

  // d_out is poisoned to 0xAA before every timed launch — zero it ourselves.
  (void)hipMemsetAsync(out, 0, sizeof(float), stream);
  dilate_softdtw_kernel<<<dim3(256), dim3(64), 0, stream>>>(outputs, targets, out);
}

// Round 5
// 90.068 us; speedup vs baseline: 2.3947x; 1.6278x over previous
//
#include <hip/hip_runtime.h>

// DILATE loss: 0.5*soft-DTW(value) + 0.5*<softDTW-grad, Omega>.
// B=64, T=128, C=4 -> M=256 independent sequences, N=128, gamma=0.01.
//
// Single fused forward pass. The temporal term sum_ij E_ij*Omega_ij is the
// directional derivative (JVP) of the soft-DTW value in direction Omega, so
// instead of forward+backward we run ONE anti-diagonal recurrence carrying
// (R, Rdot):  Rdot[i][j] = Omega[i][j] + w_diag*Rdot[i-1][j-1]
//                        + w_up*Rdot[i-1][j] + w_left*Rdot[i][j-1]
// where w_* are the softmin's normalized exp terms (free - already computed).
// One block = one wave = one sequence; lane l owns rows i0=2l+1, i1=2l+2.
// Cross-lane handoff via DPP wave_shr:1 (VALU, boundary fill via `old`).
// No W matrix, no backward loop, no reduction: lane 63's Rdot[128][128]
// IS sum(E*Omega). LDS usage: 1.5 KB (t/o staging only).

#define TN 128
#define BATCH 64
#define CH 4

__device__ __forceinline__ float fast_exp2(float x) { return __builtin_amdgcn_exp2f(x); }
__device__ __forceinline__ float fast_log2(float x) { return __builtin_amdgcn_logf(x); }
__device__ __forceinline__ float fast_rcp(float x)  { return __builtin_amdgcn_rcpf(x); }

// lane i <- lane i-1, lane 0 <- fill   (DPP wave_shr:1)
__device__ __forceinline__ float dpp_shr1(float x, float fill) {
  union { float f; int i; } o, s, r;
  o.f = fill; s.f = x;
  r.i = __builtin_amdgcn_update_dpp(o.i, s.i, 0x138, 0xF, 0xF, false);
  return r.f;
}

__global__ __launch_bounds__(64)
void dilate_softdtw_kernel(const float* __restrict__ outputs,
                           const float* __restrict__ targets,
                           float* __restrict__ out) {
  // [0,128) = t, [128,256) = o, [256,384) = zeroed pad so the masked lanes'
  // out-of-range o reads hit finite in-bounds data.
  __shared__ float buf[384];
  float* t_s = buf;
  float* o_s = buf + 128;

  const float BIG  = 100000000.0f;
  const float K2   = 144.2695040888963f;      // (1/gamma)*log2(e)
  const float GLN2 = 0.006931471805599453f;   // gamma*ln(2)

  const int m = blockIdx.x, b = m >> 2, c = m & 3;
  const int lane = threadIdx.x;   // 0..63
  const int i0 = 2*lane + 1;      // rows i0, i1=i0+1

  const float* tb = targets + (size_t)b*(TN*CH) + c;
  const float* ob = outputs + (size_t)b*(TN*CH) + c;
  t_s[lane]      = tb[lane*CH];
  t_s[lane + 64] = tb[(lane + 64)*CH];
  o_s[lane]      = ob[lane*CH];
  o_s[lane + 64] = ob[(lane + 64)*CH];
  buf[256 + lane] = 0.0f;
  buf[320 + lane] = 0.0f;
  __syncthreads();

  const float t0 = t_s[i0 - 1];   // t[i0]
  const float t1 = t_s[i0];       // t[i1]

  // ---- peel d=2: cell (1,1) = D[1][1], Rdot[1][1] = Omega[1][1] = 0 ----
  float p1_0, p1_1 = BIG, p2_0 = BIG, up2 = BIG;           // R diagonals
  float dp1_0 = 0.f, dp1_1 = 0.f, dp2_0 = 0.f, dup2 = 0.f; // Rdot diagonals
  {
    float df = t0 - o_s[0];
    p1_0 = (lane == 0) ? df*df : BIG;
  }
  float fd0 = (float)(2*i0 - 3);  // i0 - j0 at d=3
  float fd1 = fd0 + 2.0f;         // i1 - j1

  #pragma unroll 2
  for (int d = 3; d <= 2*TN; ++d) {
    const int j0 = d - i0;            // c0 column; c1 column = j0-1
    const float o0 = o_s[j0 - 1];     // masked lanes read pad/garbage: benign
    const float o1 = o_s[j0 - 2];
    float up1  = dpp_shr1(p1_1, BIG); // R[i0-1][j0]    (row 0 -> BIG)
    float dup1 = dpp_shr1(dp1_1, 0.f);// Rdot[i0-1][j0] (row 0 -> 0)

    // ---- cell (i1, j1=j0-1): preds diag=p2_0, up=p1_0, left=p1_1 ----
    float mn1 = fminf(p2_0, fminf(p1_0, p1_1));
    float h1  = mn1 * K2;
    float ea1 = fast_exp2(__builtin_fmaf(-K2, p2_0, h1));
    float eb1 = fast_exp2(__builtin_fmaf(-K2, p1_0, h1));
    float ec1 = fast_exp2(__builtin_fmaf(-K2, p1_1, h1));
    float sum1 = (ea1 + eb1) + ec1;
    float rs1 = fast_rcp(sum1);
    float s1  = __builtin_fmaf(-GLN2, fast_log2(sum1), mn1);
    float df1 = t1 - o1;
    const bool ok1 = ((unsigned)(j0 - 2)) <= 127u;
    float c1v = ok1 ? __builtin_fmaf(df1, df1, s1) : BIG;
    float jv1 = __builtin_fmaf(ea1, dp2_0, __builtin_fmaf(eb1, dp1_0, ec1 * dp1_1));
    float d1v = ok1 ? __builtin_fmaf(rs1, jv1, fd1*fd1) : 0.f;

    // ---- cell (i0, j0): preds diag=up2, up=up1, left=p1_0 ----
    float mn0 = fminf(up2, fminf(up1, p1_0));
    float h0  = mn0 * K2;
    float ea0 = fast_exp2(__builtin_fmaf(-K2, up2, h0));
    float eb0 = fast_exp2(__builtin_fmaf(-K2, up1, h0));
    float ec0 = fast_exp2(__builtin_fmaf(-K2, p1_0, h0));
    float sum0 = (ea0 + eb0) + ec0;
    float rs0 = fast_rcp(sum0);
    float s0  = __builtin_fmaf(-GLN2, fast_log2(sum0), mn0);
    float df0 = t0 - o0;
    const bool ok0 = ((unsigned)(j0 - 1)) <= 127u;
    float c0v = ok0 ? __builtin_fmaf(df0, df0, s0) : BIG;
    float jv0 = __builtin_fmaf(ea0, dup2, __builtin_fmaf(eb0, dup1, ec0 * dp1_0));
    float d0v = ok0 ? __builtin_fmaf(rs0, jv0, fd0*fd0) : 0.f;

    // rotate register pipelines
    p2_0 = p1_0;  p1_0 = c0v;  p1_1 = c1v;  up2 = up1;
    dp2_0 = dp1_0; dp1_0 = d0v; dp1_1 = d1v; dup2 = dup1;
    fd0 -= 1.0f; fd1 -= 1.0f;
  }

  // lane 63 holds cell (128,128): R = soft-DTW value, Rdot = sum(E*Omega).
  if (lane == 63) {
    // 0.5*R/B + 0.5*Rdot/(B*T*T)
    const float partial = p1_1 * 0.0078125f + dp1_1 * 4.76837158203125e-7f;
    atomicAdd(out, partial);
  }
}

extern "C" void kernel_launch(void* const* d_in, const int* in_sizes, int n_in,
                              void* d_out, int out_size, void* d_ws, size_t ws_size,
                              hipStream_t stream) {
  const float* outputs = (const float*)d_in[0];   // [64,128,4]
  const float* targets = (const float*)d_in[1];   // [64,128,4]
  float* out = (float*)d_out;                     // scalar fp32
  (void)in_sizes; (void)n_in; (void)out_size; (void)d_ws; (void)ws_size;

  // d_out is poisoned to 0xAA before every timed launch — zero it ourselves.
  (void)hipMemsetAsync(out, 0, sizeof(float), stream);
  dilate_softdtw_kernel<<<dim3(256), dim3(64), 0, stream>>>(outputs, targets, out);
}

// Round 6
// 86.297 us; speedup vs baseline: 2.4994x; 1.0437x over previous
//
#include <hip/hip_runtime.h>

// DILATE loss: 0.5*soft-DTW(value) + 0.5*<softDTW-grad, Omega>.
// B=64, T=128, C=4 -> M=256 independent sequences, N=128, gamma=0.01.
//
// Single fused forward pass carrying (R, Rdot) where Rdot = JVP of soft-DTW
// value in direction Omega (== sum E*Omega). One block = one wave = one
// sequence; lane l owns rows i0=2l+1, i1=2l+2; cross-lane handoff via DPP
// wave_shr:1.
//
// R6 changes vs R5:
//  - no boundary masking: o is staged into a padded LDS array whose sentinel
//    pads (o_pad=15 -> D_pad ~100..400) make out-of-range cells a growing
//    "wall"; any real cell gives wall predecessors weight exp2(<=-14000)=0
//    exactly. WALL init/fill = 3e4 (NOT 1e8): must keep x*K2 <= ~1.5e7 so
//    ulp(h) << 1, else exp2(fma(-K2,x,h)) can round to +inf.
//  - only ONE LDS read per iteration (o[j0-2] next iter = o[j0-1] this iter,
//    register-rotated), prefetched a full iteration ahead -> latency hidden.

#define TN 128
#define BATCH 64
#define CH 4

__device__ __forceinline__ float fast_exp2(float x) { return __builtin_amdgcn_exp2f(x); }
__device__ __forceinline__ float fast_log2(float x) { return __builtin_amdgcn_logf(x); }
__device__ __forceinline__ float fast_rcp(float x)  { return __builtin_amdgcn_rcpf(x); }

// lane i <- lane i-1, lane 0 <- fill   (DPP wave_shr:1) — HW-verified R4/R5
__device__ __forceinline__ float dpp_shr1(float x, float fill) {
  union { float f; int i; } o, s, r;
  o.f = fill; s.f = x;
  r.i = __builtin_amdgcn_update_dpp(o.i, s.i, 0x138, 0xF, 0xF, false);
  return r.f;
}

__global__ __launch_bounds__(64)
void dilate_softdtw_kernel(const float* __restrict__ outputs,
                           const float* __restrict__ targets,
                           float* __restrict__ out) {
  // padded o: valid indices oc[-126..254]; pads hold O_PAD sentinel.
  __shared__ float obuf[384];

  const float WALL  = 30000.0f;   // boundary wall (3e4*K2=4.3e6: ulp<=0.5, safe)
  const float O_PAD = 15.0f;      // (t - 15)^2 ~ 100..400 per OOB step
  const float K2    = 144.2695040888963f;     // (1/gamma)*log2(e)
  const float GLN2  = 0.006931471805599453f;  // gamma*ln(2)

  const int m = blockIdx.x, b = m >> 2, c = m & 3;
  const int lane = threadIdx.x;   // 0..63
  const int i0 = 2*lane + 1;      // rows i0, i1=i0+1

  const float* tb = targets + (size_t)b*(TN*CH) + c;
  const float* ob = outputs + (size_t)b*(TN*CH) + c;

  // stage padded o
  #pragma unroll
  for (int s = 0; s < 6; ++s) {
    const int idx = lane + 64*s;
    const int k = idx - 126;
    obuf[idx] = ((unsigned)k <= 127u) ? ob[k*CH] : O_PAD;
  }
  const float t0 = tb[(i0 - 1)*CH];   // t[i0]
  const float t1 = tb[i0*CH];         // t[i1]
  __syncthreads();

  const float* oc = obuf + 126;       // oc[k] = o[k] for k in [0,128)

  // ---- peel d=2: cell (1,1) = D[1][1]; Rdot[1][1] = Omega[1][1] = 0 ----
  float p1_0, p1_1 = WALL, p2_0 = WALL, up2 = WALL;          // R diagonals
  float dp1_0 = 0.f, dp1_1 = 0.f, dp2_0 = 0.f, dup2 = 0.f;   // Rdot diagonals
  {
    float df = t0 - oc[0];
    p1_0 = (lane == 0) ? df*df : WALL;
  }
  float fd0 = (float)(2*i0 - 3);  // i0 - j0 at d=3
  float fd1 = fd0 + 2.0f;         // i1 - j1
  float o0 = oc[2 - i0];          // o[j0-1] at d=3
  float o1 = oc[1 - i0];          // o[j0-2] at d=3

  #pragma unroll 2
  for (int d = 3; d <= 2*TN; ++d) {
    const int j0 = d - i0;
    const float o_nxt = oc[j0];        // prefetch: next iter's o[j0-1]
    float up1  = dpp_shr1(p1_1, WALL); // R[i0-1][j0]    (row 0 -> wall)
    float dup1 = dpp_shr1(dp1_1, 0.f); // Rdot[i0-1][j0] (row 0 -> 0, weight 0)

    // ---- cell (i1, j1=j0-1): preds diag=p2_0, up=p1_0, left=p1_1 ----
    float mn1 = fminf(p2_0, fminf(p1_0, p1_1));
    float h1  = mn1 * K2;
    float ea1 = fast_exp2(__builtin_fmaf(-K2, p2_0, h1));
    float eb1 = fast_exp2(__builtin_fmaf(-K2, p1_0, h1));
    float ec1 = fast_exp2(__builtin_fmaf(-K2, p1_1, h1));
    float sum1 = (ea1 + eb1) + ec1;
    float rs1 = fast_rcp(sum1);
    float s1  = __builtin_fmaf(-GLN2, fast_log2(sum1), mn1);
    float df1 = t1 - o1;
    float c1v = __builtin_fmaf(df1, df1, s1);
    float jv1 = __builtin_fmaf(ea1, dp2_0, __builtin_fmaf(eb1, dp1_0, ec1 * dp1_1));
    float d1v = __builtin_fmaf(rs1, jv1, fd1*fd1);

    // ---- cell (i0, j0): preds diag=up2, up=up1, left=p1_0 ----
    float mn0 = fminf(up2, fminf(up1, p1_0));
    float h0  = mn0 * K2;
    float ea0 = fast_exp2(__builtin_fmaf(-K2, up2, h0));
    float eb0 = fast_exp2(__builtin_fmaf(-K2, up1, h0));
    float ec0 = fast_exp2(__builtin_fmaf(-K2, p1_0, h0));
    float sum0 = (ea0 + eb0) + ec0;
    float rs0 = fast_rcp(sum0);
    float s0  = __builtin_fmaf(-GLN2, fast_log2(sum0), mn0);
    float df0 = t0 - o0;
    float c0v = __builtin_fmaf(df0, df0, s0);
    float jv0 = __builtin_fmaf(ea0, dup2, __builtin_fmaf(eb0, dup1, ec0 * dp1_0));
    float d0v = __builtin_fmaf(rs0, jv0, fd0*fd0);

    // rotate register pipelines
    p2_0 = p1_0;   p1_0 = c0v;  p1_1 = c1v;  up2 = up1;
    dp2_0 = dp1_0; dp1_0 = d0v; dp1_1 = d1v; dup2 = dup1;
    o1 = o0; o0 = o_nxt;
    fd0 -= 1.0f; fd1 -= 1.0f;
  }

  // lane 63 cell (128,128): R = soft-DTW value, Rdot = sum(E*Omega).
  if (lane == 63) {
    // 0.5*R/B + 0.5*Rdot/(B*T*T)
    const float partial = p1_1 * 0.0078125f + dp1_1 * 4.76837158203125e-7f;
    atomicAdd(out, partial);
  }
}

extern "C" void kernel_launch(void* const* d_in, const int* in_sizes, int n_in,
                              void* d_out, int out_size, void* d_ws, size_t ws_size,
                              hipStream_t stream) {
  const float* outputs = (const float*)d_in[0];   // [64,128,4]
  const float* targets = (const float*)d_in[1];   // [64,128,4]
  float* out = (float*)d_out;                     // scalar fp32
  (void)in_sizes; (void)n_in; (void)out_size; (void)d_ws; (void)ws_size;

  // d_out is poisoned to 0xAA before every timed launch — zero it ourselves.
  (void)hipMemsetAsync(out, 0, sizeof(float), stream);
  dilate_softdtw_kernel<<<dim3(256), dim3(64), 0, stream>>>(outputs, targets, out);
}

// Round 7
// 86.069 us; speedup vs baseline: 2.5060x; 1.0027x over previous
//
#include <hip/hip_runtime.h>

// DILATE loss: 0.5*soft-DTW(value) + 0.5*<softDTW-grad, Omega>.
// B=64, T=128, C=4 -> M=256 independent sequences, N=128, gamma=0.01.
//
// Single fused forward pass carrying (R', Rdot) where Rdot = JVP of the
// soft-DTW value in direction Omega (== sum E*Omega), and R' = -K2*R is the
// log2-scaled negated value. Since K2*(gamma*ln2) == 1 exactly:
//   R'[i][j] = fma(-K2, D[i][j], max3(preds') + log2(sum of exp2(pred'-max)))
// -> no per-cell mul for the exp scale, min3 becomes v_max3_f32, exp args are
// plain subs. Weights for the Rdot update are the same exp2 terms * rcp(sum).
// One block = one wave = one sequence; lane l owns rows i0=2l+1, i1=i0+1;
// cross-lane handoff via DPP wave_shr:1. Boundary handling via sentinel-padded
// o (wall cells' weights flush to exactly 0 in any real cell). Source is
// manually interleaved across the two cells (args -> 6x exp2 -> sums ->
// rcp/log2 -> values -> Rdot fmas) so transcendental latency is covered by
// the sibling cell's independent instructions (single in-order wave/SIMD).

#define TN 128
#define BATCH 64
#define CH 4

__device__ __forceinline__ float fast_exp2(float x) { return __builtin_amdgcn_exp2f(x); }
__device__ __forceinline__ float fast_log2(float x) { return __builtin_amdgcn_logf(x); }
__device__ __forceinline__ float fast_rcp(float x)  { return __builtin_amdgcn_rcpf(x); }

// lane i <- lane i-1, lane 0 <- fill   (DPP wave_shr:1) — HW-verified R4-R6
__device__ __forceinline__ float dpp_shr1(float x, float fill) {
  union { float f; int i; } o, s, r;
  o.f = fill; s.f = x;
  r.i = __builtin_amdgcn_update_dpp(o.i, s.i, 0x138, 0xF, 0xF, false);
  return r.f;
}

__global__ __launch_bounds__(64)
void dilate_softdtw_kernel(const float* __restrict__ outputs,
                           const float* __restrict__ targets,
                           float* __restrict__ out) {
  // padded o: oc[k]=o[k] for k in [0,128); pads hold O_PAD sentinel.
  __shared__ float obuf[384];

  const float WALLP = -4.328085e6f;  // -K2*30000: wall in scaled units
  const float O_PAD = 15.0f;         // (t-15)^2 ~ 100..400 per OOB step
  const float K2    = 144.2695040888963f;     // (1/gamma)*log2(e)

  const int m = blockIdx.x, b = m >> 2, c = m & 3;
  const int lane = threadIdx.x;   // 0..63
  const int i0 = 2*lane + 1;      // rows i0, i1=i0+1

  const float* tb = targets + (size_t)b*(TN*CH) + c;
  const float* ob = outputs + (size_t)b*(TN*CH) + c;

  #pragma unroll
  for (int s = 0; s < 6; ++s) {
    const int idx = lane + 64*s;
    const int k = idx - 126;
    obuf[idx] = ((unsigned)k <= 127u) ? ob[k*CH] : O_PAD;
  }
  const float t0 = tb[(i0 - 1)*CH];   // t[i0]
  const float t1 = tb[i0*CH];         // t[i1]
  __syncthreads();

  const float* oc = obuf + 126;

  // ---- peel d=2: R'(1,1) = -K2*D(1,1); Rdot(1,1) = Omega(1,1) = 0 ----
  float p1_0, p1_1 = WALLP, p2_0 = WALLP, up2 = WALLP;       // R' diagonals
  float dp1_0 = 0.f, dp1_1 = 0.f, dp2_0 = 0.f, dup2 = 0.f;   // Rdot diagonals
  {
    float df = t0 - oc[0];
    p1_0 = (lane == 0) ? -K2*df*df : WALLP;
  }
  float fd0 = (float)(2*i0 - 3);  // i0 - j0 at d=3
  float fd1 = fd0 + 2.0f;         // i1 - j1
  float o0 = oc[2 - i0];          // o[j0-1] at d=3
  float o1 = oc[1 - i0];          // o[j0-2] at d=3

  #pragma unroll 2
  for (int d = 3; d <= 2*TN; ++d) {
    const int j0 = d - i0;
    const float o_nxt = oc[j0];          // prefetch next iter's o[j0-1]
    float up1  = dpp_shr1(p1_1, WALLP);  // R'[i0-1][j0]    (row 0 -> wall)
    float dup1 = dpp_shr1(dp1_1, 0.f);   // Rdot[i0-1][j0]  (weight = 0 anyway)

    // --- exp args, both cells (max3 = single v_max3_f32) ---
    float mn1 = fmaxf(p2_0, fmaxf(p1_0, p1_1));   // cell (i1, j0-1)
    float mn0 = fmaxf(up2,  fmaxf(up1,  p1_0));   // cell (i0, j0)
    float a1 = p2_0 - mn1, b1 = p1_0 - mn1, c1 = p1_1 - mn1;
    float a0 = up2  - mn0, b0 = up1  - mn0, c0 = p1_0 - mn0;

    // --- 6 exp2 back-to-back: issue covers latency of the first ones ---
    float ea1 = fast_exp2(a1);
    float eb1 = fast_exp2(b1);
    float ec1 = fast_exp2(c1);
    float ea0 = fast_exp2(a0);
    float eb0 = fast_exp2(b0);
    float ec0 = fast_exp2(c0);

    float sum1 = (ea1 + eb1) + ec1;
    float sum0 = (ea0 + eb0) + ec0;
    float rs1 = fast_rcp(sum1);
    float rs0 = fast_rcp(sum0);
    float l1  = fast_log2(sum1);
    float l0  = fast_log2(sum0);

    // --- independent work while rcp/log are in flight ---
    float df1 = t1 - o1, df0 = t0 - o0;
    float q1 = df1*df1,  q0 = df0*df0;
    float jv1 = __builtin_fmaf(ea1, dp2_0, __builtin_fmaf(eb1, dp1_0, ec1*dp1_1));
    float jv0 = __builtin_fmaf(ea0, dup2,  __builtin_fmaf(eb0, dup1,  ec0*dp1_0));
    float w1 = fd1*fd1, w0 = fd0*fd0;

    // --- values (scaled): R' = -K2*q + (mn + log2(sum)) ---
    float c1v = __builtin_fmaf(-K2, q1, mn1 + l1);
    float c0v = __builtin_fmaf(-K2, q0, mn0 + l0);
    // --- Rdot: normalized weighted sum + Omega ---
    float d1v = __builtin_fmaf(rs1, jv1, w1);
    float d0v = __builtin_fmaf(rs0, jv0, w0);

    // rotate register pipelines
    p2_0 = p1_0;   p1_0 = c0v;  p1_1 = c1v;  up2 = up1;
    dp2_0 = dp1_0; dp1_0 = d0v; dp1_1 = d1v; dup2 = dup1;
    o1 = o0; o0 = o_nxt;
    fd0 -= 1.0f; fd1 -= 1.0f;
  }

  // lane 63 holds cell (128,128): R = -gamma*ln2 * R', Rdot = sum(E*Omega).
  if (lane == 63) {
    // 0.5*R/B + 0.5*Rdot/(B*T*T);  0.5*(gamma*ln2)/64 = 5.4152123e-5
    const float partial = __builtin_fmaf(p1_1, -5.415212348e-5f,
                                         dp1_1 * 4.76837158203125e-7f);
    atomicAdd(out, partial);
  }
}

extern "C" void kernel_launch(void* const* d_in, const int* in_sizes, int n_in,
                              void* d_out, int out_size, void* d_ws, size_t ws_size,
                              hipStream_t stream) {
  const float* outputs = (const float*)d_in[0];   // [64,128,4]
  const float* targets = (const float*)d_in[1];   // [64,128,4]
  float* out = (float*)d_out;                     // scalar fp32
  (void)in_sizes; (void)n_in; (void)out_size; (void)d_ws; (void)ws_size;

  // d_out is poisoned to 0xAA before every timed launch — zero it ourselves.
  (void)hipMemsetAsync(out, 0, sizeof(float), stream);
  dilate_softdtw_kernel<<<dim3(256), dim3(64), 0, stream>>>(outputs, targets, out);
}